// Round 9
// baseline (47.197 us; speedup 1.0000x reference)
//
#include <hip/hip_runtime.h>
#include <math.h>

#define BB 2
#define NN 1024
#define HH 4
#define F_IN 128
#define HID 32
#define TJ 64
#define NT (NN/TJ)     // 16 j-tiles, one u64 mask word each

typedef unsigned long long u64;

// ---- workspace layout (bytes) ----
#define WS_X    0              // f32 x [bh][n][k]          = 1048576
#define WS_X4   1048576        // f32 planes [bh][q][n][4]  = 1048576
#define WS_D6   2097152        // f32 [bh][n]               = 32768
#define WS_BITS 2129920        // u64 [b][n][NT]            = 262144  (end 2392064)

// ---------------- Kernel 1: proj (x=feat@W) + plane copy + d6 + adjacency bit-pack
// (R8-verbatim)
__global__ __launch_bounds__(128) void gat_proj_kernel(const float* __restrict__ feat,
        const float* __restrict__ W, const float* __restrict__ Wa, const int* __restrict__ adj,
        float* __restrict__ xout, float* __restrict__ x4, float* __restrict__ d6,
        u64* __restrict__ bits) {
    const int RPB = 2;
    int blk = blockIdx.x;              // 0 .. BB*NN/2-1
    int b  = blk / (NN / RPB);
    int n0 = (blk % (NN / RPB)) * RPB;
    int t  = threadIdx.x;              // 0..127 -> output column h*32+k

    __shared__ float fs[RPB][F_IN];
    fs[0][t] = feat[((size_t)(b*NN + n0    ))*F_IN + t];
    fs[1][t] = feat[((size_t)(b*NN + n0 + 1))*F_IN + t];
    __syncthreads();

    float a0 = 0.f, a1 = 0.f;
    for (int f = 0; f < F_IN; ++f) {
        float w = W[f*(HH*HID) + t];
        a0 = fmaf(fs[0][f], w, a0);
        a1 = fmaf(fs[1][f], w, a1);
    }
    int h = t >> 5, k = t & 31;
    int bh = b*HH + h;
    xout[((size_t)bh*NN + n0    )*HID + k] = a0;
    xout[((size_t)bh*NN + n0 + 1)*HID + k] = a1;
    // k-quad-major planes: float idx (bh*8 + k/4)*4096 + n*4 + k%4
    x4[((size_t)bh*8 + (k >> 2))*(NN*4) + (n0    )*4 + (k & 3)] = a0;
    x4[((size_t)bh*8 + (k >> 2))*(NN*4) + (n0 + 1)*4 + (k & 3)] = a1;

    float w_t = Wa[t];
    float p0 = a0*w_t, p1 = a1*w_t;
#pragma unroll
    for (int off = 16; off >= 1; off >>= 1) {
        p0 += __shfl_xor(p0, off, 32);
        p1 += __shfl_xor(p1, off, 32);
    }
    if (k == 0) {
        d6[(size_t)bh*NN + n0    ] = 0.6f*p0;
        d6[(size_t)bh*NN + n0 + 1] = 0.6f*p1;
    }
    // adjacency bit-pack for this block's 2 rows
#pragma unroll
    for (int r = 0; r < RPB; ++r) {
        const int* arow = adj + ((size_t)(b*NN + n0 + r))*NN;
        u64* brow = bits + ((size_t)(b*NN + n0 + r))*NT;
#pragma unroll
        for (int c0 = 0; c0 < NN; c0 += 128) {
            u64 m = __ballot(arow[c0 + t] > 0);
            if ((t & 63) == 0) brow[(c0 + t) >> 6] = m;
        }
    }
}

// ---------------- Kernel 2: fused attention. 256 thr (4 waves), 2 rows/wave, 8 rows/block.
// R8-verbatim compute core and epilogue; ONLY change: explicit 2-deep register
// double-buffer of the xj/dj/mask stream (prefetch tile t+1 during tile t's compute).
#define PREFETCH(XJ, DJ, MA, MB, T) { \
    const int jn = (T)*TJ + l; \
    _Pragma("unroll") \
    for (int q = 0; q < 8; ++q) XJ[q] = xq[q*NN + jn]; \
    DJ = dbh[jn]; \
    MA = brA[T]; \
    MB = brB[T]; \
}

#define COMPUTE(XJ, DJ, MA, MB) { \
    float sA0 = 0.f, sA1 = 0.f, sA2 = 0.f, sA3 = 0.f; \
    float sB0 = 0.f, sB1 = 0.f, sB2 = 0.f, sB3 = 0.f; \
    _Pragma("unroll") \
    for (int q = 0; q < 8; ++q) { \
        float4 xv = XJ[q]; \
        float v; \
        v = xiA[4*q+0] + xv.x; sA0 = fmaf(wa4[4*q+0], fabsf(v), sA0); \
        v = xiA[4*q+1] + xv.y; sA1 = fmaf(wa4[4*q+1], fabsf(v), sA1); \
        v = xiA[4*q+2] + xv.z; sA2 = fmaf(wa4[4*q+2], fabsf(v), sA2); \
        v = xiA[4*q+3] + xv.w; sA3 = fmaf(wa4[4*q+3], fabsf(v), sA3); \
        v = xiB[4*q+0] + xv.x; sB0 = fmaf(wa4[4*q+0], fabsf(v), sB0); \
        v = xiB[4*q+1] + xv.y; sB1 = fmaf(wa4[4*q+1], fabsf(v), sB1); \
        v = xiB[4*q+2] + xv.z; sB2 = fmaf(wa4[4*q+2], fabsf(v), sB2); \
        v = xiB[4*q+3] + xv.w; sB3 = fmaf(wa4[4*q+3], fabsf(v), sB3); \
    } \
    float eA = (ciA + DJ) + ((sA0 + sA1) + (sA2 + sA3)); \
    float eB = (ciB + DJ) + ((sB0 + sB1) + (sB2 + sB3)); \
    float pA = ((MA >> l) & 1ull) ? __expf(eA) : 0.f; \
    float pB = ((MB >> l) & 1ull) ? __expf(eB) : 0.f; \
    lsA += pA; \
    lsB += pB; \
    _Pragma("unroll") \
    for (int q = 0; q < 8; ++q) { \
        float4 xv = XJ[q]; \
        accA[4*q+0] = fmaf(pA, xv.x, accA[4*q+0]); \
        accA[4*q+1] = fmaf(pA, xv.y, accA[4*q+1]); \
        accA[4*q+2] = fmaf(pA, xv.z, accA[4*q+2]); \
        accA[4*q+3] = fmaf(pA, xv.w, accA[4*q+3]); \
        accB[4*q+0] = fmaf(pB, xv.x, accB[4*q+0]); \
        accB[4*q+1] = fmaf(pB, xv.y, accB[4*q+1]); \
        accB[4*q+2] = fmaf(pB, xv.z, accB[4*q+2]); \
        accB[4*q+3] = fmaf(pB, xv.w, accB[4*q+3]); \
    } \
}

__global__ __launch_bounds__(256) void gat_attn4_kernel(const float* __restrict__ x,
                                                        const float4* __restrict__ x4,
                                                        const float* __restrict__ d6,
                                                        const u64* __restrict__ bits,
                                                        const float* __restrict__ Wa,
                                                        float* __restrict__ out) {
    const int tid = threadIdx.x;
    const int w = __builtin_amdgcn_readfirstlane(tid >> 6);   // wave id 0..3
    const int l = tid & 63;
    const int blk = blockIdx.x;                // 0..1023
    const int bh = blk >> 7;                   // 128 blocks per (b,h)
    const int i0 = (blk & 127) << 3;           // 8 rows per block
    const int h = bh & (HH - 1), b = bh >> 2;
    const int iA = i0 + 2*w, iB = iA + 1;

    const float* xbh = x  + (size_t)bh * NN * HID;
    const float* dbh = d6 + (size_t)bh * NN;
    const u64* brA = bits + ((size_t)b*NN + iA) * NT;
    const u64* brB = bits + ((size_t)b*NN + iB) * NT;
    const float4* xq = x4 + (size_t)bh * 8 * NN;   // 8 k-quad planes

    // ---- prefetch tile 0 first (longest latency), then scalar row data
    float4 xj0[8], xj1[8];
    float dj0, dj1;
    u64 m0A, m0B, m1A, m1B;
    PREFETCH(xj0, dj0, m0A, m0B, 0)

    float xiA[HID], xiB[HID], wa4[HID];
#pragma unroll
    for (int k = 0; k < HID; ++k) {
        xiA[k] = xbh[(size_t)iA*HID + k];
        xiB[k] = xbh[(size_t)iB*HID + k];
        wa4[k] = 0.4f * Wa[h*HID + k];
    }
    float ciA = dbh[iA], ciB = dbh[iB];

    float accA[HID], accB[HID];
#pragma unroll
    for (int k = 0; k < HID; ++k) { accA[k] = 0.f; accB[k] = 0.f; }
    float lsA = 0.f, lsB = 0.f;

    for (int t = 0; t < NT; t += 2) {
        PREFETCH(xj1, dj1, m1A, m1B, t + 1)
        COMPUTE(xj0, dj0, m0A, m0B)
        if (t + 2 < NT) PREFETCH(xj0, dj0, m0A, m0B, t + 2)
        COMPUTE(xj1, dj1, m1A, m1B)
    }

    // ---- epilogue (R8-verbatim): fold upper 32 lanes, reduce denominators,
    // per-wave 32x33 LDS transpose-reduce in a wave-private region (no barrier).
#pragma unroll
    for (int k = 0; k < HID; ++k) {
        accA[k] += __shfl_xor(accA[k], 32, 64);
        accB[k] += __shfl_xor(accB[k], 32, 64);
    }
#pragma unroll
    for (int off = 32; off >= 1; off >>= 1) {
        lsA += __shfl_xor(lsA, off, 64);
        lsB += __shfl_xor(lsB, off, 64);
    }
    float invA = 1.0f / lsA, invB = 1.0f / lsB;
    float* orowA = out + ((size_t)(b*NN + iA))*(HH*HID) + h*HID;
    float* orowB = out + ((size_t)(b*NN + iB))*(HH*HID) + h*HID;

    __shared__ float scr[4][32*33];        // 16.9 KB, wave-private regions
    float* sw = scr[w];
    if (l < 32) {
#pragma unroll
        for (int k = 0; k < HID; ++k) sw[k*33 + l] = accA[k];
    }
    if (l < 32) {
        float res = 0.f;
#pragma unroll
        for (int m = 0; m < 32; ++m) res += sw[l*33 + m];
        orowA[l] = res * invA;
    }
    if (l < 32) {
#pragma unroll
        for (int k = 0; k < HID; ++k) sw[k*33 + l] = accB[k];
    }
    if (l < 32) {
        float res = 0.f;
#pragma unroll
        for (int m = 0; m < 32; ++m) res += sw[l*33 + m];
        orowB[l] = res * invB;
    }
}

extern "C" void kernel_launch(void* const* d_in, const int* in_sizes, int n_in,
                              void* d_out, int out_size, void* d_ws, size_t ws_size,
                              hipStream_t stream) {
    const float* node_feat = (const float*)d_in[0];
    const int*   adj_mtx   = (const int*)d_in[1];
    const float* W         = (const float*)d_in[2];
    const float* Wa        = (const float*)d_in[3];
    float* out = (float*)d_out;

    char* ws = (char*)d_ws;
    float* x_ws  = (float*)(ws + WS_X);
    float* x4_ws = (float*)(ws + WS_X4);
    float* d6_ws = (float*)(ws + WS_D6);
    u64*   bits  = (u64*)(ws + WS_BITS);

    hipLaunchKernelGGL(gat_proj_kernel, dim3(BB*NN/2), dim3(128), 0, stream,
                       node_feat, W, Wa, adj_mtx, x_ws, x4_ws, d6_ws, bits);
    hipLaunchKernelGGL(gat_attn4_kernel, dim3(BB*HH*NN/8), dim3(256), 0, stream,
                       x_ws, (const float4*)x4_ws, d6_ws, bits, Wa, out);
}

// Round 10
// 44.804 us; speedup vs baseline: 1.0534x; 1.0534x over previous
//
#include <hip/hip_runtime.h>
#include <math.h>

#define BB 2
#define NN 1024
#define HH 4
#define F_IN 128
#define HID 32
#define TJ 64
#define NT (NN/TJ)     // 16 j-tiles, one u64 mask word each

typedef unsigned long long u64;

// ---- workspace layout (bytes) ----
#define WS_X    0              // f32 x [bh][n][k]          = 1048576
#define WS_D6   1048576        // f32 [bh][n]               = 32768
#define WS_BITS 1081344        // u64 [b][n][NT]            = 262144

// ---------------- Kernel 1: proj (x=feat@W) + d6 + adjacency bit-pack (R8-verbatim, minus x4)
__global__ __launch_bounds__(128) void gat_proj_kernel(const float* __restrict__ feat,
        const float* __restrict__ W, const float* __restrict__ Wa, const int* __restrict__ adj,
        float* __restrict__ xout, float* __restrict__ d6, u64* __restrict__ bits) {
    const int RPB = 2;
    int blk = blockIdx.x;              // 0 .. BB*NN/2-1
    int b  = blk / (NN / RPB);
    int n0 = (blk % (NN / RPB)) * RPB;
    int t  = threadIdx.x;              // 0..127 -> output column h*32+k

    __shared__ float fs[RPB][F_IN];
    fs[0][t] = feat[((size_t)(b*NN + n0    ))*F_IN + t];
    fs[1][t] = feat[((size_t)(b*NN + n0 + 1))*F_IN + t];
    __syncthreads();

    float a0 = 0.f, a1 = 0.f;
    for (int f = 0; f < F_IN; ++f) {
        float w = W[f*(HH*HID) + t];
        a0 = fmaf(fs[0][f], w, a0);
        a1 = fmaf(fs[1][f], w, a1);
    }
    int h = t >> 5, k = t & 31;
    int bh = b*HH + h;
    xout[((size_t)bh*NN + n0    )*HID + k] = a0;
    xout[((size_t)bh*NN + n0 + 1)*HID + k] = a1;

    float w_t = Wa[t];
    float p0 = a0*w_t, p1 = a1*w_t;
#pragma unroll
    for (int off = 16; off >= 1; off >>= 1) {
        p0 += __shfl_xor(p0, off, 32);
        p1 += __shfl_xor(p1, off, 32);
    }
    if (k == 0) {
        d6[(size_t)bh*NN + n0    ] = 0.6f*p0;
        d6[(size_t)bh*NN + n0 + 1] = 0.6f*p1;
    }
    // adjacency bit-pack for this block's 2 rows
#pragma unroll
    for (int r = 0; r < RPB; ++r) {
        const int* arow = adj + ((size_t)(b*NN + n0 + r))*NN;
        u64* brow = bits + ((size_t)(b*NN + n0 + r))*NT;
#pragma unroll
        for (int c0 = 0; c0 < NN; c0 += 128) {
            u64 m = __ballot(arow[c0 + t] > 0);
            if ((t & 63) == 0) brow[(c0 + t) >> 6] = m;
        }
    }
}

// ---------------- Kernel 2: fused attention. 512 thr (8 waves), ONE query row per wave.
// lane = j within the LDS tile (R6-proven staging); xi/wa/ci wave-uniform -> SGPRs;
// per-lane VGPR footprint = acc[32] + transient xj -> high residency.
// Fixed m=0 softmax; proven fold+butterfly+transpose epilogue (2 rounds, xs reuse).
__global__ __launch_bounds__(512) void gat_attn5_kernel(const float* __restrict__ x,
                                                        const float* __restrict__ d6,
                                                        const u64* __restrict__ bits,
                                                        const float* __restrict__ Wa,
                                                        float* __restrict__ out) {
    const int tid = threadIdx.x;
    const int w = __builtin_amdgcn_readfirstlane(tid >> 6);   // wave id 0..7
    const int l = tid & 63;
    const int blk = blockIdx.x;                // 0..1023
    const int bh = blk >> 7;                   // 128 blocks per (b,h)
    const int i0 = (blk & 127) << 3;           // 8 rows per block
    const int h = bh & (HH - 1), b = bh >> 2;
    const int i = i0 + w;                      // this wave's query row (uniform)

    const float* xbh = x  + (size_t)bh * NN * HID;
    const float* dbh = d6 + (size_t)bh * NN;
    const u64* brow = bits + ((size_t)b*NN + i) * NT;

    // wave-uniform row data (uniform addresses -> scalar loads/SGPRs)
    float xi[HID], wa4[HID];
#pragma unroll
    for (int k = 0; k < HID; ++k) {
        xi[k]  = xbh[(size_t)i*HID + k];
        wa4[k] = 0.4f * Wa[h*HID + k];
    }
    float ci = dbh[i];

    __shared__ float xs[2][TJ][36];     // 18.4 KB, pad 36 -> conflict-free b128 (R6-proven)

    float acc[HID];
#pragma unroll
    for (int k = 0; k < HID; ++k) acc[k] = 0.f;
    float lsum = 0.f;

    // staging: tile = 64 rows x 32 floats = 512 float4; 512 threads x 1 (R3-proven geometry)
    const int r0 = tid >> 3, q0 = (tid & 7) << 2;
    const float4* gsrc = (const float4*)xbh;
    float4 pre = gsrc[tid];             // prefetch tile 0

    for (int t = 0; t < NT; ++t) {
        const int bc = t & 1;
        *(float4*)&xs[bc][r0][q0] = pre;
        __syncthreads();
        if (t + 1 < NT) pre = gsrc[(t + 1)*512 + tid];

        u64 wM = brow[t];
        float dj = dbh[t*TJ + l];

        float4 xj4[8];
#pragma unroll
        for (int q = 0; q < 8; ++q) xj4[q] = *(const float4*)&xs[bc][l][4*q];

        // e = 0.6*(d_i+d_j) + sum_k 0.4*wa_k*|x_i+x_j|  (== wa . lrelu(x_i+x_j))
        float s0 = 0.f, s1 = 0.f, s2 = 0.f, s3 = 0.f;
#pragma unroll
        for (int q = 0; q < 8; ++q) {
            float4 xv = xj4[q];
            float v;
            v = xi[4*q+0] + xv.x; s0 = fmaf(wa4[4*q+0], fabsf(v), s0);
            v = xi[4*q+1] + xv.y; s1 = fmaf(wa4[4*q+1], fabsf(v), s1);
            v = xi[4*q+2] + xv.z; s2 = fmaf(wa4[4*q+2], fabsf(v), s2);
            v = xi[4*q+3] + xv.w; s3 = fmaf(wa4[4*q+3], fabsf(v), s3);
        }
        float e = (ci + dj) + ((s0 + s1) + (s2 + s3));
        float p = ((wM >> l) & 1ull) ? __expf(e) : 0.f;   // fixed m=0
        lsum += p;
#pragma unroll
        for (int q = 0; q < 8; ++q) {
            float4 xv = xj4[q];
            acc[4*q+0] = fmaf(p, xv.x, acc[4*q+0]);
            acc[4*q+1] = fmaf(p, xv.y, acc[4*q+1]);
            acc[4*q+2] = fmaf(p, xv.z, acc[4*q+2]);
            acc[4*q+3] = fmaf(p, xv.w, acc[4*q+3]);
        }
    }

    // ---- epilogue (proven pieces): fold upper 32 lanes, butterfly denominator,
    // per-wave 32x33 transpose-reduce reusing xs (2 rounds of 4 regions).
#pragma unroll
    for (int k = 0; k < HID; ++k) acc[k] += __shfl_xor(acc[k], 32, 64);
#pragma unroll
    for (int off = 32; off >= 1; off >>= 1) lsum += __shfl_xor(lsum, off, 64);
    float inv = 1.0f / lsum;
    float* orow = out + ((size_t)(b*NN + i))*(HH*HID) + h*HID;

    __syncthreads();                       // all tile reads done; xs reusable
    float* xsf = (float*)xs;               // 4608 floats; 4 regions x 1056 = 4224
    float* sw = xsf + (w & 3) * (32*33);
    if (w < 4) {
        if (l < 32) {
#pragma unroll
            for (int k = 0; k < HID; ++k) sw[k*33 + l] = acc[k];
        }
        if (l < 32) {
            float res = 0.f;
#pragma unroll
            for (int m = 0; m < 32; ++m) res += sw[l*33 + m];
            orow[l] = res * inv;
        }
    }
    __syncthreads();
    if (w >= 4) {
        if (l < 32) {
#pragma unroll
            for (int k = 0; k < HID; ++k) sw[k*33 + l] = acc[k];
        }
        if (l < 32) {
            float res = 0.f;
#pragma unroll
            for (int m = 0; m < 32; ++m) res += sw[l*33 + m];
            orow[l] = res * inv;
        }
    }
}

extern "C" void kernel_launch(void* const* d_in, const int* in_sizes, int n_in,
                              void* d_out, int out_size, void* d_ws, size_t ws_size,
                              hipStream_t stream) {
    const float* node_feat = (const float*)d_in[0];
    const int*   adj_mtx   = (const int*)d_in[1];
    const float* W         = (const float*)d_in[2];
    const float* Wa        = (const float*)d_in[3];
    float* out = (float*)d_out;

    char* ws = (char*)d_ws;
    float* x_ws  = (float*)(ws + WS_X);
    float* d6_ws = (float*)(ws + WS_D6);
    u64*   bits  = (u64*)(ws + WS_BITS);

    hipLaunchKernelGGL(gat_proj_kernel, dim3(BB*NN/2), dim3(128), 0, stream,
                       node_feat, W, Wa, adj_mtx, x_ws, d6_ws, bits);
    hipLaunchKernelGGL(gat_attn5_kernel, dim3(BB*HH*NN/8), dim3(512), 0, stream,
                       x_ws, d6_ws, bits, Wa, out);
}